// Round 11
// baseline (82.202 us; speedup 1.0000x reference)
//
#include <hip/hip_runtime.h>
#include <hip/hip_bf16.h>

// KANLinear as fragment-direct bf16 MFMA GEMM (R10 skeleton, 16-row blocks):
//   y = A @ W'^T + skip_b
//   A (2048 x 4352) VIRTUAL: per dim d, 16 hat weights max(0,1-|t-k|),
//     t=(clamp(x)+1)*7.5 (cols 0..4095), then 256 cols clamp(x) (skip).
//     A tiles (16 rows x 32 k) built cooperatively in LDS per block-step,
//     double-buffered, 1 barrier/step, shared by all 4 waves.
//   W' (256 x 4352) bf16, PRE-PERMUTED into MFMA B-fragment order (Wf):
//     chunk(kb,og,q,n) = W'[og*16+n][kb*32+q*8 .. +8]; a wave loads a 16x32
//     B-frag as one coalesced global_load_dwordx4 (lane = q*16+n).
// Block = 16 rows x 256 cols (4 waves, wave tile 16x64, acc[4]).
// 5 K-splits: 4 knot splits (32 kblocks = 64 dims each) + 1 skip split (8 kb).
// fp32 partials in tile-blocked layout (1KB-coalesced stores) -> reduce(+bias).

namespace {
constexpr int Bsz  = 2048;
constexpr int Din  = 256;
constexpr int Dout = 256;
constexpr int Kn   = 16;
constexpr int KKNOT = Din * Kn;        // 4096
constexpr int Ksp   = KKNOT + Din;     // 4352
constexpr int KB    = Ksp / 32;        // 136 k-blocks of 32
constexpr int KBK   = KKNOT / 32;      // 128 knot k-blocks
constexpr float INV_H = 7.5f;          // 1 / (2/15)
constexpr float Hgrid = 2.0f / 15.0f;

constexpr int NSPLIT = 5;              // 4 knot splits + 1 skip split
constexpr int SPSK   = 32;             // kblocks per knot split (64 dims)
constexpr int SPSS   = 8;              // kblocks in the skip split
constexpr int PELEM  = Bsz * Dout;     // 524288 floats per split partial
constexpr int SXS    = 68;             // sx row stride (floats)
}

typedef __attribute__((ext_vector_type(8))) short shortx8;   // 8 bf16 = 4 VGPR
typedef __attribute__((ext_vector_type(4))) float floatx4;   // MFMA acc

__device__ __forceinline__ unsigned int f2bf(float f) {
  __hip_bfloat16 h = __float2bfloat16(f);
  return (unsigned int)*reinterpret_cast<unsigned short*>(&h);
}
__device__ __forceinline__ float clamp1(float v) {
  return fminf(1.f, fmaxf(-1.f, v));
}
// Pack two pre-rounded f32 bit patterns (already +0x8000) into bf16x2.
__device__ __forceinline__ unsigned int packbf(unsigned int e0, unsigned int e1) {
  return (e1 & 0xffff0000u) | (e0 >> 16);
}
__device__ __forceinline__ unsigned int rnd(float f) {
  return __float_as_uint(f) + 0x8000u;
}

// --- Prep: permute W' into B-fragment order. 544 blocks x 256. ---
__global__ __launch_bounds__(256) void kan_prep(
    const float* __restrict__ values, const float* __restrict__ skip_w,
    unsigned short* __restrict__ Wf) {
  const int tid = blockIdx.x * 256 + threadIdx.x;   // 139264 total
  const int q  = tid & 3;
  const int n  = (tid >> 2) & 15;
  const int og = (tid >> 6) & 15;
  const int kb = tid >> 10;
  const int o  = og * 16 + n;
  const int k0 = kb * 32 + q * 8;
  const float* src = (kb < KBK)
      ? values + (size_t)o * KKNOT + k0
      : skip_w + (size_t)o * Din + (k0 - KKNOT);
  const float4 v0 = *(const float4*)src;
  const float4 v1 = *(const float4*)(src + 4);
  const size_t chunk = (size_t)kb * 1024 + og * 64 + q * 16 + n;
  *(uint4*)(Wf + chunk * 8) = make_uint4(
      f2bf(v0.x) | (f2bf(v0.y) << 16), f2bf(v0.z) | (f2bf(v0.w) << 16),
      f2bf(v1.x) | (f2bf(v1.y) << 16), f2bf(v1.z) | (f2bf(v1.w) << 16));
}

// --- GEMM: grid = 128 mi x 5 ks = 640 blocks, 256 thr (4 waves). ---
__global__ __launch_bounds__(256) void kan_gemm(
    const float* __restrict__ x, const unsigned short* __restrict__ Wf,
    float* __restrict__ part) {
  __shared__ float sx[16 * SXS];                            // x slice, 4.25 KB
  __shared__ __align__(16) unsigned short aLds[2][16 * 32]; // A tiles, 2x1 KB

  const int tid  = threadIdx.x;
  const int wave = tid >> 6, lane = tid & 63;
  const int ks   = blockIdx.x % NSPLIT;
  const int mi   = blockIdx.x / NSPLIT;
  const int m0   = mi * 16;
  const int og0  = wave * 4;                     // this wave's 64 out-cols
  const int lrow = lane & 15, lq = lane >> 4;

  // Cooperative A-build mapping: thread -> (row, col pair 2*bcol2).
  const int brow  = tid >> 4;                    // 0..15
  const int bcol2 = tid & 15;                    // cols 2*bcol2, 2*bcol2+1
  const int dsel  = bcol2 >> 3;                  // which of 2 dims in a kblock
  const float h0  = (float)(2 * (bcol2 & 7));    // hat base within dim

  const uint4* B = (const uint4*)Wf;             // chunk = kb*1024 + og*64 + lane

  floatx4 acc[4] = {};
  uint4 bb[2][4];

  if (ks < 4) {
    // ============ Knot split: 32 kblocks, dims d0..d0+63. ============
    const int kb0 = ks * SPSK;
    const int d0  = ks * 64;
    // Stage x slice: one float4 per thread (row = tid>>4, seg = tid&15).
    {
      const float4 v = *(const float4*)(x + (size_t)(m0 + brow) * Din + d0 + bcol2 * 4);
      *(float4*)&sx[brow * SXS + bcol2 * 4] = v;
    }
    __syncthreads();

    // Prolog: prefetch kb0's B-frags and build A-tile buf 0.
    #pragma unroll
    for (int j = 0; j < 4; ++j)
      bb[0][j] = B[(size_t)kb0 * 1024 + (og0 + j) * 64 + lane];
    {
      const float xv = sx[brow * SXS + dsel];    // dims 0,1 for s=0
      const float t  = (clamp1(xv) + 1.f) * INV_H;
      const unsigned int e0 = rnd(fmaxf(0.f, 1.f - fabsf(t - h0)));
      const unsigned int e1 = rnd(fmaxf(0.f, 1.f - fabsf(t - (h0 + 1.f))));
      *(unsigned int*)&aLds[0][brow * 32 + 2 * bcol2] = packbf(e0, e1);
    }

    for (int s = 0; s < SPSK; ++s) {
      const int cur = s & 1, nxt = cur ^ 1;
      // Prefetch next B-frags.
      if (s + 1 < SPSK) {
        #pragma unroll
        for (int j = 0; j < 4; ++j)
          bb[nxt][j] = B[(size_t)(kb0 + s + 1) * 1024 + (og0 + j) * 64 + lane];
      }
      __syncthreads();   // aLds[cur] visible; prior reads of nxt done

      // Build NEXT A-tile (from LDS sx, no global dependency).
      if (s + 1 < SPSK) {
        const float xv = sx[brow * SXS + 2 * (s + 1) + dsel];
        const float t  = (clamp1(xv) + 1.f) * INV_H;
        const unsigned int e0 = rnd(fmaxf(0.f, 1.f - fabsf(t - h0)));
        const unsigned int e1 = rnd(fmaxf(0.f, 1.f - fabsf(t - (h0 + 1.f))));
        *(unsigned int*)&aLds[nxt][brow * 32 + 2 * bcol2] = packbf(e0, e1);
      }

      // A-frag (ds_read_b128) + 4 MFMA.
      const shortx8 af = *(const shortx8*)&aLds[cur][lrow * 32 + lq * 8];
      #pragma unroll
      for (int j = 0; j < 4; ++j) {
        union { uint4 u; shortx8 s; } bc;
        bc.u = bb[cur][j];
        acc[j] = __builtin_amdgcn_mfma_f32_16x16x32_bf16(af, bc.s, acc[j], 0, 0, 0);
      }
    }
  } else {
    // ============ Skip split: 8 kblocks of clamp(x) columns. ============
    const int kb0 = KBK;
    float2 px[2];
    #pragma unroll
    for (int j = 0; j < 4; ++j)
      bb[0][j] = B[(size_t)kb0 * 1024 + (og0 + j) * 64 + lane];
    px[0] = *(const float2*)(x + (size_t)(m0 + brow) * Din + 2 * bcol2);
    *(unsigned int*)&aLds[0][brow * 32 + 2 * bcol2] =
        packbf(rnd(clamp1(px[0].x)), rnd(clamp1(px[0].y)));

    for (int s = 0; s < SPSS; ++s) {
      const int cur = s & 1, nxt = cur ^ 1;
      if (s + 1 < SPSS) {
        #pragma unroll
        for (int j = 0; j < 4; ++j)
          bb[nxt][j] = B[(size_t)(kb0 + s + 1) * 1024 + (og0 + j) * 64 + lane];
        px[nxt] = *(const float2*)(x + (size_t)(m0 + brow) * Din + (s + 1) * 32 + 2 * bcol2);
      }
      __syncthreads();

      if (s + 1 < SPSS) {
        *(unsigned int*)&aLds[nxt][brow * 32 + 2 * bcol2] =
            packbf(rnd(clamp1(px[nxt].x)), rnd(clamp1(px[nxt].y)));
      }

      const shortx8 af = *(const shortx8*)&aLds[cur][lrow * 32 + lq * 8];
      #pragma unroll
      for (int j = 0; j < 4; ++j) {
        union { uint4 u; shortx8 s; } bc;
        bc.u = bb[cur][j];
        acc[j] = __builtin_amdgcn_mfma_f32_16x16x32_bf16(af, bc.s, acc[j], 0, 0, 0);
      }
    }
  }

  // Epilogue: tile-blocked partials; each store = 64 lanes x 16B = 1KB coalesced.
  // wtile = mi*4 + wave; P[ks][wtile][(j*64 + lane)*4 + r]
  const int wtile = mi * 4 + wave;
  float* P = part + (size_t)ks * PELEM + (size_t)wtile * 1024;
  #pragma unroll
  for (int j = 0; j < 4; ++j)
    *(floatx4*)&P[(j * 64 + lane) * 4] = acc[j];
}

// --- Reduce 5 tile-blocked partials + bias -> out. 512 blocks x 256. ---
__global__ __launch_bounds__(256) void kan_reduce(
    const float* __restrict__ part, const float* __restrict__ skip_b,
    float* __restrict__ out) {
  const int tid = blockIdx.x * 256 + threadIdx.x;   // float4 index, 131072 total
  float4 a = make_float4(0.f, 0.f, 0.f, 0.f);
  #pragma unroll
  for (int s = 0; s < NSPLIT; ++s) {
    const float4 p = *(const float4*)(part + (size_t)s * PELEM + (size_t)tid * 4);
    a.x += p.x; a.y += p.y; a.z += p.z; a.w += p.w;
  }
  // Decode tile-blocked layout back to (b, o).
  const int f4    = tid & 255, wtile = tid >> 8;
  const int j     = f4 >> 6,  lane  = f4 & 63;
  const int mi    = wtile >> 2;
  const int wave  = wtile & 3;
  const int b0    = mi * 16 + (lane >> 4) * 4;
  const int o     = wave * 64 + j * 16 + (lane & 15);
  const float sb  = skip_b[o];
  out[(size_t)(b0 + 0) * Dout + o] = a.x + sb;
  out[(size_t)(b0 + 1) * Dout + o] = a.y + sb;
  out[(size_t)(b0 + 2) * Dout + o] = a.z + sb;
  out[(size_t)(b0 + 3) * Dout + o] = a.w + sb;
}

// ---------------- Fallback (round-1 structure, needs 4.4 MB ws) ----------------
__device__ __forceinline__ void knot_interp(float xraw, float& xv, float& w, int& l) {
  xv = fminf(1.0f, fmaxf(-1.0f, xraw));
  float t = (xv + 1.0f) * INV_H;
  l = (int)ceilf(t) - 1;
  l = l < 0 ? 0 : (l > Kn - 2 ? Kn - 2 : l);
  float g0 = -1.0f + Hgrid * (float)l;
  w = (xv - g0) * INV_H;
}

__global__ __launch_bounds__(256) void prep_transpose(
    const float* __restrict__ values, const float* __restrict__ skip_w,
    float* __restrict__ vt, float* __restrict__ swt) {
  int idx = blockIdx.x * blockDim.x + threadIdx.x;
  if (idx < Din * Kn * Dout) {
    int k = idx & (Kn - 1);
    int d = (idx >> 4) & (Din - 1);
    int o = idx >> 12;
    vt[(d * Kn + k) * Dout + o] = values[idx];
  }
  if (idx < Dout * Din) {
    int d = idx & (Din - 1);
    int o = idx >> 8;
    swt[d * Dout + o] = skip_w[idx];
  }
}

__global__ __launch_bounds__(256) void kan_main(
    const float* __restrict__ x, const float* __restrict__ vt,
    const float* __restrict__ swt, const float* __restrict__ skip_b,
    float* __restrict__ out) {
  __shared__ float s_w[4][Din];
  __shared__ float s_x[4][Din];
  __shared__ int   s_l[4][Din];
  const int tid = threadIdx.x;
  const int b0  = blockIdx.x * 4;
  for (int i = tid; i < 4 * Din; i += 256) {
    int bb = i >> 8;
    int d  = i & (Din - 1);
    float xv, w; int l;
    knot_interp(x[(b0 + bb) * Din + d], xv, w, l);
    s_w[bb][d] = w; s_x[bb][d] = xv; s_l[bb][d] = l;
  }
  __syncthreads();
  const int g = tid >> 6, lane = tid & 63;
  const int o = lane << 2, b = b0 + g;
  float4 acc = make_float4(0.f, 0.f, 0.f, 0.f);
  for (int d = 0; d < Din; ++d) {
    const float w = s_w[g][d], xv = s_x[g][d];
    const int l = s_l[g][d];
    const float* base = vt + (d * Kn + l) * Dout + o;
    const float4 vl = *(const float4*)(base);
    const float4 vr = *(const float4*)(base + Dout);
    const float4 sw = *(const float4*)(swt + d * Dout + o);
    acc.x = fmaf(xv, sw.x, fmaf(w, vr.x - vl.x, acc.x + vl.x));
    acc.y = fmaf(xv, sw.y, fmaf(w, vr.y - vl.y, acc.y + vl.y));
    acc.z = fmaf(xv, sw.z, fmaf(w, vr.z - vl.z, acc.z + vl.z));
    acc.w = fmaf(xv, sw.w, fmaf(w, vr.w - vl.w, acc.w + vl.w));
  }
  const float4 bias = *(const float4*)(skip_b + o);
  acc.x += bias.x; acc.y += bias.y; acc.z += bias.z; acc.w += bias.w;
  *(float4*)(out + (size_t)b * Dout + o) = acc;
}

extern "C" void kernel_launch(void* const* d_in, const int* in_sizes, int n_in,
                              void* d_out, int out_size, void* d_ws, size_t ws_size,
                              hipStream_t stream) {
  (void)in_sizes; (void)n_in; (void)out_size;
  const float* x      = (const float*)d_in[0];
  const float* values = (const float*)d_in[1];
  const float* skip_w = (const float*)d_in[2];
  const float* skip_b = (const float*)d_in[3];
  float* out = (float*)d_out;

  const size_t wf_bytes   = (size_t)Dout * Ksp * sizeof(unsigned short);   // 2.23 MB
  const size_t part_bytes = (size_t)NSPLIT * PELEM * sizeof(float);        // 10.5 MB
  const size_t need_gemm  = wf_bytes + part_bytes;
  const size_t need_fb    = (size_t)(Din * Kn * Dout + Din * Dout) * sizeof(float);

  if (ws_size >= need_gemm) {
    unsigned short* Wf = (unsigned short*)d_ws;
    float* part = (float*)((char*)d_ws + wf_bytes);
    kan_prep<<<(KB * 1024) / 256, 256, 0, stream>>>(values, skip_w, Wf);
    kan_gemm<<<(Bsz / 16) * NSPLIT, 256, 0, stream>>>(x, Wf, part);
    kan_reduce<<<PELEM / 4 / 256, 256, 0, stream>>>(part, skip_b, out);
  } else if (ws_size >= need_fb) {
    float* vt  = (float*)d_ws;
    float* swt = vt + Din * Kn * Dout;
    prep_transpose<<<(Din * Kn * Dout + 255) / 256, 256, 0, stream>>>(values, skip_w, vt, swt);
    kan_main<<<Bsz / 4, 256, 0, stream>>>(x, vt, swt, skip_b, out);
  }
}

// Round 12
// 78.036 us; speedup vs baseline: 1.0534x; 1.0534x over previous
//
#include <hip/hip_runtime.h>
#include <hip/hip_bf16.h>

// KANLinear as fragment-direct bf16 MFMA GEMM (R10 skeleton, BK=64):
//   y = A @ W'^T + skip_b
//   A (2048 x 4352) VIRTUAL: per dim d, 16 hat weights max(0,1-|t-k|),
//     t=(clamp(x)+1)*7.5 (cols 0..4095), then 256 cols clamp(x) (skip).
//     A tiles (32 rows x 64 k = 2 kblocks) built cooperatively in LDS per
//     block-step, double-buffered, 1 barrier/step, shared by all 4 waves.
//   W' (256 x 4352) bf16, PRE-PERMUTED into MFMA B-fragment order (Wf):
//     chunk(kb,og,q,n) = W'[og*16+n][kb*32+q*8 .. +8]; a wave loads a 16x32
//     B-frag as one coalesced global_load_dwordx4 (lane = q*16+n).
// Block = 32 rows x 256 cols (4 waves x 64 cols), wave tile 32x64, acc[2][4].
// 9 K-splits: 8 knot splits (16 kblocks = 8 steps of 2) + 1 skip split (8 kb
// = 4 steps of 2). fp32 partials, tile-blocked (1KB-coalesced) -> reduce(+bias).

namespace {
constexpr int Bsz  = 2048;
constexpr int Din  = 256;
constexpr int Dout = 256;
constexpr int Kn   = 16;
constexpr int KKNOT = Din * Kn;        // 4096
constexpr int Ksp   = KKNOT + Din;     // 4352
constexpr int KB    = Ksp / 32;        // 136 k-blocks of 32
constexpr int KBK   = KKNOT / 32;      // 128 knot k-blocks
constexpr float INV_H = 7.5f;          // 1 / (2/15)
constexpr float Hgrid = 2.0f / 15.0f;

constexpr int NSPLIT = 9;              // 8 knot splits + 1 skip split
constexpr int STK    = 8;              // steps per knot split (2 kblocks each)
constexpr int STS    = 4;              // steps in the skip split
constexpr int PELEM  = Bsz * Dout;     // 524288 floats per split partial
constexpr int SXS    = 36;             // sx row stride (floats) -> conflict-free
}

typedef __attribute__((ext_vector_type(8))) short shortx8;   // 8 bf16 = 4 VGPR
typedef __attribute__((ext_vector_type(4))) float floatx4;   // MFMA acc

__device__ __forceinline__ unsigned int f2bf(float f) {
  __hip_bfloat16 h = __float2bfloat16(f);
  return (unsigned int)*reinterpret_cast<unsigned short*>(&h);
}
__device__ __forceinline__ float clamp1(float v) {
  return fminf(1.f, fmaxf(-1.f, v));
}
// Pack two pre-rounded f32 bit patterns (already +0x8000) into bf16x2.
__device__ __forceinline__ unsigned int packbf(unsigned int e0, unsigned int e1) {
  return (e1 & 0xffff0000u) | (e0 >> 16);
}
__device__ __forceinline__ unsigned int rnd(float f) {
  return __float_as_uint(f) + 0x8000u;
}

// --- Prep: permute W' into B-fragment order. 544 blocks x 256. ---
__global__ __launch_bounds__(256) void kan_prep(
    const float* __restrict__ values, const float* __restrict__ skip_w,
    unsigned short* __restrict__ Wf) {
  const int tid = blockIdx.x * 256 + threadIdx.x;   // 139264 total
  const int q  = tid & 3;
  const int n  = (tid >> 2) & 15;
  const int og = (tid >> 6) & 15;
  const int kb = tid >> 10;
  const int o  = og * 16 + n;
  const int k0 = kb * 32 + q * 8;
  const float* src = (kb < KBK)
      ? values + (size_t)o * KKNOT + k0
      : skip_w + (size_t)o * Din + (k0 - KKNOT);
  const float4 v0 = *(const float4*)src;
  const float4 v1 = *(const float4*)(src + 4);
  const size_t chunk = (size_t)kb * 1024 + og * 64 + q * 16 + n;
  *(uint4*)(Wf + chunk * 8) = make_uint4(
      f2bf(v0.x) | (f2bf(v0.y) << 16), f2bf(v0.z) | (f2bf(v0.w) << 16),
      f2bf(v1.x) | (f2bf(v1.y) << 16), f2bf(v1.z) | (f2bf(v1.w) << 16));
}

// --- GEMM: grid = 64 mi x 9 ks = 576 blocks, 256 thr (4 waves). ---
__global__ __launch_bounds__(256) void kan_gemm(
    const float* __restrict__ x, const unsigned short* __restrict__ Wf,
    float* __restrict__ part) {
  __shared__ float sx[32 * SXS];                            // x slice, 4.6 KB
  __shared__ __align__(16) unsigned short aLds[2][32 * 64]; // A tiles, 2x4 KB

  const int tid  = threadIdx.x;
  const int wave = tid >> 6, lane = tid & 63;
  const int ks   = blockIdx.x % NSPLIT;
  const int mi   = blockIdx.x / NSPLIT;
  const int m0   = mi * 32;
  const int og0  = wave * 4;                     // this wave's 64 out-cols
  const int lrow = lane & 15, lq = lane >> 4;

  // Cooperative A-build mapping: thread -> (row, 8-col segment of 64).
  const int brow = tid >> 3;                     // 0..31
  const int bseg = tid & 7;                      // cols bseg*8 .. +7
  const int kbi  = bseg >> 2;                    // which kblock of the pair
  const int dsel = (bseg >> 1) & 1;              // which of 2 dims in a kblock
  const float h0 = (float)((bseg & 1) * 8);      // hat base within dim

  const uint4* B = (const uint4*)Wf;             // chunk = kb*1024 + og*64 + lane

  floatx4 acc[2][4] = {};
  uint4 bb[2][8];

  if (ks < 8) {
    // ============ Knot split: 16 kblocks = 8 steps, dims d0..d0+31. ============
    const int kb0 = ks * 16;
    const int d0  = ks * 32;
    // Stage x slice: one float4 per thread (row = tid>>3, seg = tid&7).
    {
      const float4 v = *(const float4*)(x + (size_t)(m0 + brow) * Din + d0 + bseg * 4);
      *(float4*)&sx[brow * SXS + bseg * 4] = v;
    }
    __syncthreads();

    // Prolog: prefetch step-0 B-frags (2 kblocks) and build A-tile buf 0.
    #pragma unroll
    for (int kk = 0; kk < 2; ++kk)
      #pragma unroll
      for (int j = 0; j < 4; ++j)
        bb[0][kk * 4 + j] = B[(size_t)(kb0 + kk) * 1024 + (og0 + j) * 64 + lane];
    {
      const float xv = sx[brow * SXS + 2 * kbi + dsel];   // dims 0..3 for s=0
      const float t  = (clamp1(xv) + 1.f) * INV_H;
      unsigned int e[8];
      #pragma unroll
      for (int h = 0; h < 8; ++h)
        e[h] = rnd(fmaxf(0.f, 1.f - fabsf(t - (h0 + (float)h))));
      *(uint4*)&aLds[0][brow * 64 + bseg * 8] =
          make_uint4(packbf(e[0], e[1]), packbf(e[2], e[3]),
                     packbf(e[4], e[5]), packbf(e[6], e[7]));
    }

    for (int s = 0; s < STK; ++s) {
      const int cur = s & 1, nxt = cur ^ 1;
      // Prefetch next step's B-frags (2 kblocks).
      if (s + 1 < STK) {
        #pragma unroll
        for (int kk = 0; kk < 2; ++kk)
          #pragma unroll
          for (int j = 0; j < 4; ++j)
            bb[nxt][kk * 4 + j] =
                B[(size_t)(kb0 + 2 * (s + 1) + kk) * 1024 + (og0 + j) * 64 + lane];
      }
      __syncthreads();   // aLds[cur] visible; prior reads of nxt done

      // Build NEXT A-tile (from LDS sx, no global dependency).
      if (s + 1 < STK) {
        const float xv = sx[brow * SXS + 4 * (s + 1) + 2 * kbi + dsel];
        const float t  = (clamp1(xv) + 1.f) * INV_H;
        unsigned int e[8];
        #pragma unroll
        for (int h = 0; h < 8; ++h)
          e[h] = rnd(fmaxf(0.f, 1.f - fabsf(t - (h0 + (float)h))));
        *(uint4*)&aLds[nxt][brow * 64 + bseg * 8] =
            make_uint4(packbf(e[0], e[1]), packbf(e[2], e[3]),
                       packbf(e[4], e[5]), packbf(e[6], e[7]));
      }

      // A-frags (ds_read_b128) + 16 MFMA.
      shortx8 af[2][2];
      #pragma unroll
      for (int i = 0; i < 2; ++i)
        #pragma unroll
        for (int kk = 0; kk < 2; ++kk)
          af[i][kk] = *(const shortx8*)&aLds[cur][(16 * i + lrow) * 64 + kk * 32 + lq * 8];
      #pragma unroll
      for (int kk = 0; kk < 2; ++kk)
        #pragma unroll
        for (int j = 0; j < 4; ++j) {
          union { uint4 u; shortx8 s; } bc;
          bc.u = bb[cur][kk * 4 + j];
          #pragma unroll
          for (int i = 0; i < 2; ++i)
            acc[i][j] = __builtin_amdgcn_mfma_f32_16x16x32_bf16(af[i][kk], bc.s, acc[i][j], 0, 0, 0);
        }
    }
  } else {
    // ============ Skip split: 8 kblocks = 4 steps of clamp(x) columns. ============
    const int kb0 = KBK;
    const float* xrow = x + (size_t)(m0 + brow) * Din;
    float4 pxa[2], pxb[2];
    #pragma unroll
    for (int kk = 0; kk < 2; ++kk)
      #pragma unroll
      for (int j = 0; j < 4; ++j)
        bb[0][kk * 4 + j] = B[(size_t)(kb0 + kk) * 1024 + (og0 + j) * 64 + lane];
    pxa[0] = *(const float4*)(xrow + bseg * 8);
    pxb[0] = *(const float4*)(xrow + bseg * 8 + 4);
    {
      unsigned int e[8];
      e[0] = rnd(clamp1(pxa[0].x)); e[1] = rnd(clamp1(pxa[0].y));
      e[2] = rnd(clamp1(pxa[0].z)); e[3] = rnd(clamp1(pxa[0].w));
      e[4] = rnd(clamp1(pxb[0].x)); e[5] = rnd(clamp1(pxb[0].y));
      e[6] = rnd(clamp1(pxb[0].z)); e[7] = rnd(clamp1(pxb[0].w));
      *(uint4*)&aLds[0][brow * 64 + bseg * 8] =
          make_uint4(packbf(e[0], e[1]), packbf(e[2], e[3]),
                     packbf(e[4], e[5]), packbf(e[6], e[7]));
    }

    for (int s = 0; s < STS; ++s) {
      const int cur = s & 1, nxt = cur ^ 1;
      if (s + 1 < STS) {
        #pragma unroll
        for (int kk = 0; kk < 2; ++kk)
          #pragma unroll
          for (int j = 0; j < 4; ++j)
            bb[nxt][kk * 4 + j] =
                B[(size_t)(kb0 + 2 * (s + 1) + kk) * 1024 + (og0 + j) * 64 + lane];
        pxa[nxt] = *(const float4*)(xrow + (s + 1) * 64 + bseg * 8);
        pxb[nxt] = *(const float4*)(xrow + (s + 1) * 64 + bseg * 8 + 4);
      }
      __syncthreads();

      if (s + 1 < STS) {
        unsigned int e[8];
        e[0] = rnd(clamp1(pxa[nxt].x)); e[1] = rnd(clamp1(pxa[nxt].y));
        e[2] = rnd(clamp1(pxa[nxt].z)); e[3] = rnd(clamp1(pxa[nxt].w));
        e[4] = rnd(clamp1(pxb[nxt].x)); e[5] = rnd(clamp1(pxb[nxt].y));
        e[6] = rnd(clamp1(pxb[nxt].z)); e[7] = rnd(clamp1(pxb[nxt].w));
        *(uint4*)&aLds[nxt][brow * 64 + bseg * 8] =
            make_uint4(packbf(e[0], e[1]), packbf(e[2], e[3]),
                       packbf(e[4], e[5]), packbf(e[6], e[7]));
      }

      shortx8 af[2][2];
      #pragma unroll
      for (int i = 0; i < 2; ++i)
        #pragma unroll
        for (int kk = 0; kk < 2; ++kk)
          af[i][kk] = *(const shortx8*)&aLds[cur][(16 * i + lrow) * 64 + kk * 32 + lq * 8];
      #pragma unroll
      for (int kk = 0; kk < 2; ++kk)
        #pragma unroll
        for (int j = 0; j < 4; ++j) {
          union { uint4 u; shortx8 s; } bc;
          bc.u = bb[cur][kk * 4 + j];
          #pragma unroll
          for (int i = 0; i < 2; ++i)
            acc[i][j] = __builtin_amdgcn_mfma_f32_16x16x32_bf16(af[i][kk], bc.s, acc[i][j], 0, 0, 0);
        }
    }
  }

  // Epilogue: tile-blocked partials; each store = 64 lanes x 16B = 1KB coalesced.
  // wtile = mi*4 + wave; P[ks][wtile][((i*4+j)*64 + lane)*4 + r]
  const int wtile = mi * 4 + wave;
  float* P = part + (size_t)ks * PELEM + (size_t)wtile * 2048;
  #pragma unroll
  for (int i = 0; i < 2; ++i)
    #pragma unroll
    for (int j = 0; j < 4; ++j)
      *(floatx4*)&P[((i * 4 + j) * 64 + lane) * 4] = acc[i][j];
}

// --- Reduce 9 tile-blocked partials + bias -> out. 512 blocks x 256. ---
__global__ __launch_bounds__(256) void kan_reduce(
    const float* __restrict__ part, const float* __restrict__ skip_b,
    float* __restrict__ out) {
  const int tid = blockIdx.x * 256 + threadIdx.x;   // float4 index, 131072 total
  float4 a = make_float4(0.f, 0.f, 0.f, 0.f);
  #pragma unroll
  for (int s = 0; s < NSPLIT; ++s) {
    const float4 p = *(const float4*)(part + (size_t)s * PELEM + (size_t)tid * 4);
    a.x += p.x; a.y += p.y; a.z += p.z; a.w += p.w;
  }
  // Decode tile-blocked layout back to (b, o).
  const int f4    = tid & 511, wtile = tid >> 9;
  const int ij    = f4 >> 6,  lane  = f4 & 63;
  const int i     = ij >> 2,  j     = ij & 3;
  const int mi    = wtile >> 2;
  const int wave  = wtile & 3;
  const int b0    = mi * 32 + 16 * i + (lane >> 4) * 4;
  const int o     = wave * 64 + 16 * j + (lane & 15);
  const float sb  = skip_b[o];
  out[(size_t)(b0 + 0) * Dout + o] = a.x + sb;
  out[(size_t)(b0 + 1) * Dout + o] = a.y + sb;
  out[(size_t)(b0 + 2) * Dout + o] = a.z + sb;
  out[(size_t)(b0 + 3) * Dout + o] = a.w + sb;
}

// ---------------- Fallback (round-1 structure, needs 4.4 MB ws) ----------------
__device__ __forceinline__ void knot_interp(float xraw, float& xv, float& w, int& l) {
  xv = fminf(1.0f, fmaxf(-1.0f, xraw));
  float t = (xv + 1.0f) * INV_H;
  l = (int)ceilf(t) - 1;
  l = l < 0 ? 0 : (l > Kn - 2 ? Kn - 2 : l);
  float g0 = -1.0f + Hgrid * (float)l;
  w = (xv - g0) * INV_H;
}

__global__ __launch_bounds__(256) void prep_transpose(
    const float* __restrict__ values, const float* __restrict__ skip_w,
    float* __restrict__ vt, float* __restrict__ swt) {
  int idx = blockIdx.x * blockDim.x + threadIdx.x;
  if (idx < Din * Kn * Dout) {
    int k = idx & (Kn - 1);
    int d = (idx >> 4) & (Din - 1);
    int o = idx >> 12;
    vt[(d * Kn + k) * Dout + o] = values[idx];
  }
  if (idx < Dout * Din) {
    int d = idx & (Din - 1);
    int o = idx >> 8;
    swt[d * Dout + o] = skip_w[idx];
  }
}

__global__ __launch_bounds__(256) void kan_main(
    const float* __restrict__ x, const float* __restrict__ vt,
    const float* __restrict__ swt, const float* __restrict__ skip_b,
    float* __restrict__ out) {
  __shared__ float s_w[4][Din];
  __shared__ float s_x[4][Din];
  __shared__ int   s_l[4][Din];
  const int tid = threadIdx.x;
  const int b0  = blockIdx.x * 4;
  for (int i = tid; i < 4 * Din; i += 256) {
    int bb = i >> 8;
    int d  = i & (Din - 1);
    float xv, w; int l;
    knot_interp(x[(b0 + bb) * Din + d], xv, w, l);
    s_w[bb][d] = w; s_x[bb][d] = xv; s_l[bb][d] = l;
  }
  __syncthreads();
  const int g = tid >> 6, lane = tid & 63;
  const int o = lane << 2, b = b0 + g;
  float4 acc = make_float4(0.f, 0.f, 0.f, 0.f);
  for (int d = 0; d < Din; ++d) {
    const float w = s_w[g][d], xv = s_x[g][d];
    const int l = s_l[g][d];
    const float* base = vt + (d * Kn + l) * Dout + o;
    const float4 vl = *(const float4*)(base);
    const float4 vr = *(const float4*)(base + Dout);
    const float4 sw = *(const float4*)(swt + d * Dout + o);
    acc.x = fmaf(xv, sw.x, fmaf(w, vr.x - vl.x, acc.x + vl.x));
    acc.y = fmaf(xv, sw.y, fmaf(w, vr.y - vl.y, acc.y + vl.y));
    acc.z = fmaf(xv, sw.z, fmaf(w, vr.z - vl.z, acc.z + vl.z));
    acc.w = fmaf(xv, sw.w, fmaf(w, vr.w - vl.w, acc.w + vl.w));
  }
  const float4 bias = *(const float4*)(skip_b + o);
  acc.x += bias.x; acc.y += bias.y; acc.z += bias.z; acc.w += bias.w;
  *(float4*)(out + (size_t)b * Dout + o) = acc;
}

extern "C" void kernel_launch(void* const* d_in, const int* in_sizes, int n_in,
                              void* d_out, int out_size, void* d_ws, size_t ws_size,
                              hipStream_t stream) {
  (void)in_sizes; (void)n_in; (void)out_size;
  const float* x      = (const float*)d_in[0];
  const float* values = (const float*)d_in[1];
  const float* skip_w = (const float*)d_in[2];
  const float* skip_b = (const float*)d_in[3];
  float* out = (float*)d_out;

  const size_t wf_bytes   = (size_t)Dout * Ksp * sizeof(unsigned short);   // 2.23 MB
  const size_t part_bytes = (size_t)NSPLIT * PELEM * sizeof(float);        // 18.9 MB
  const size_t need_gemm  = wf_bytes + part_bytes;
  const size_t need_fb    = (size_t)(Din * Kn * Dout + Din * Dout) * sizeof(float);

  if (ws_size >= need_gemm) {
    unsigned short* Wf = (unsigned short*)d_ws;
    float* part = (float*)((char*)d_ws + wf_bytes);
    kan_prep<<<(KB * 1024) / 256, 256, 0, stream>>>(values, skip_w, Wf);
    kan_gemm<<<(Bsz / 32) * NSPLIT, 256, 0, stream>>>(x, Wf, part);
    kan_reduce<<<PELEM / 4 / 256, 256, 0, stream>>>(part, skip_b, out);
  } else if (ws_size >= need_fb) {
    float* vt  = (float*)d_ws;
    float* swt = vt + Din * Kn * Dout;
    prep_transpose<<<(Din * Kn * Dout + 255) / 256, 256, 0, stream>>>(values, skip_w, vt, swt);
    kan_main<<<Bsz / 4, 256, 0, stream>>>(x, vt, swt, skip_b, out);
  }
}